// Round 14
// baseline (167.813 us; speedup 1.0000x reference)
//
#include <hip/hip_runtime.h>
#include <hip/hip_bf16.h>

// SegFormerXAttention: B=2, LV=1024, LT=512, D=1024, H=16, DH=64
#define NH 16

typedef __attribute__((ext_vector_type(4))) float f32x4;
typedef __attribute__((ext_vector_type(8))) __bf16 bf16x8;

#define SCL2E 0.18033688011112042f   // (1/sqrt(64)) * log2(e)

__device__ __forceinline__ short f2bs(float f) {
  union { __bf16 h; short s; } x; x.h = (__bf16)f; return x.s;
}
__device__ __forceinline__ unsigned pack2(float a, float b) {
  union { __bf16 h[2]; unsigned u; } x;
  x.h[0] = (__bf16)a; x.h[1] = (__bf16)b; return x.u;
}
__device__ __forceinline__ float bs2f(unsigned short u) {
  union { unsigned u; float f; } x; x.u = (unsigned)u << 16; return x.f;
}

__device__ __forceinline__ f32x4 mfma16(bf16x8 a, bf16x8 b, f32x4 c) {
  return __builtin_amdgcn_mfma_f32_16x16x32_bf16(a, b, c, 0, 0, 0);
}

// async global->LDS, 16B per lane. LDS dest = wave-uniform base + lane*16.
__device__ __forceinline__ void gload16(const void* g, void* lds) {
  __builtin_amdgcn_global_load_lds(
      (const __attribute__((address_space(1))) void*)(unsigned long long)(g),
      (__attribute__((address_space(3))) void*)(unsigned)(unsigned long long)(lds),
      16, 0, 0);
}

// ---------------- weight transpose + activation conv + mask, ONE launch ----------------
struct WPtrs { const float* s[14]; };

__global__ __launch_bounds__(256) void wtrans_prep_kernel(WPtrs p, short* __restrict__ wt,
                                                          const float* __restrict__ vf, const float* __restrict__ uf,
                                                          short* __restrict__ Xv, short* __restrict__ Xu,
                                                          const int* __restrict__ vm, const int* __restrict__ um,
                                                          float* __restrict__ kmf) {
  int z = blockIdx.z;
  if (z >= 14) {
    int pid = (z - 14) * 256 + blockIdx.y * 16 + blockIdx.x;
    if (pid >= 3084) return;
    if (pid < 2048) {
      int i = pid * 256 + threadIdx.x;
      float4 v = *(const float4*)(vf + (size_t)i * 4);
      *(uint2*)(Xv + (size_t)i * 4) = make_uint2(pack2(v.x, v.y), pack2(v.z, v.w));
    } else if (pid < 3072) {
      int i = (pid - 2048) * 256 + threadIdx.x;
      float4 v = *(const float4*)(uf + (size_t)i * 4);
      *(uint2*)(Xu + (size_t)i * 4) = make_uint2(pack2(v.x, v.y), pack2(v.z, v.w));
    } else {
      int i = (pid - 3072) * 256 + threadIdx.x;
      if (i < 2 * 1536) {
        int b = i / 1536, k = i - b * 1536;
        int valid = (k < 1024) ? vm[b * 1024 + k] : um[b * 512 + (k - 1024)];
        kmf[i] = valid ? 0.0f : -1e35f;
      }
    }
    return;
  }
  __shared__ float t[64][65];
  const float* src = p.s[z];
  short* dst = wt + (size_t)z * 1024 * 1024;
  float scl = (z == 0 || z == 3 || z == 6 || z == 9) ? SCL2E : 1.0f;  // Q projections
  int kb = blockIdx.y * 64, nb = blockIdx.x * 64;
  int c = threadIdx.x & 63, r0 = threadIdx.x >> 6;
  #pragma unroll
  for (int i = 0; i < 16; i++) {
    int r = r0 + i * 4;
    t[r][c] = src[(size_t)(kb + r) * 1024 + nb + c];
  }
  __syncthreads();
  #pragma unroll
  for (int i = 0; i < 16; i++) {
    int r = r0 + i * 4;
    dst[(size_t)(nb + r) * 1024 + kb + c] = f2bs(t[c][r] * scl);
  }
}

// ---------------- 256-row staging for 256^2 proj: tile [256 rows][32 k] = 16KB, 2 loads/thread ----------------
__device__ __forceinline__ void stage256(const short* __restrict__ src, int row0, int kt,
                                         short* buf, int tid) {
  int w = tid >> 6;
  #pragma unroll
  for (int i = 0; i < 2; i++) {
    int s = i * 512 + tid;
    int row = s >> 2, c = s & 3;
    int cs = c ^ (row & 3) ^ ((row >> 2) & 3);
    gload16(src + (size_t)(row0 + row) * 1024 + kt + cs * 8,
            buf + (size_t)(i * 512 + w * 64) * 8);
  }
}

// ---------------- proj GEMM: 256x256 tile, 8 waves, 4-deep counted-vmcnt pipeline ----------------
// iter t: vmcnt(8) -> s_barrier -> ds_read(buf t&3) -> stage(t+3) -> 32 MFMA.
// vmcnt ledger: 3 stages in flight x 4 loads = 12; vmcnt(8) <=> stage(t) landed (own wave);
// barrier extends to all waves. WAR: buf[(t+3)&3] last read at iter t-1, consumed before barrier_t.
struct ProjJobs {
  const short* wt[12];
  short* dst[12];
  const float* bias[12];
  float bscl[12];
  int mode[12];    // 0 = QK layout [B,H,lrows,64] (+row off), 1 = V^T layout [B,H,64,1536] (+col off)
  int lrows[12];
  int off[12];
};

__global__ __launch_bounds__(512) void proj_gemm256(const short* __restrict__ Xv,
                                                    const short* __restrict__ Xu, ProjJobs jb) {
  __shared__ short As[4][256 * 32];   // 64 KB
  __shared__ short Bs[4][256 * 32];   // 64 KB  (total 128 KB, 1 block/CU)
  int w0 = blockIdx.x;                       // 288 blocks
  int f = (w0 & 7) * 36 + (w0 >> 3);         // XCD-chunk swizzle (288 % 8 == 0)
  int jz, rem, lqShift;
  const short* X;
  if (f < 192) { jz = f >> 5; rem = f & 31; X = Xv; lqShift = 10; }        // vid: 8mt x 4nt
  else { int f2 = f - 192; jz = 6 + (f2 >> 4); rem = f2 & 15; X = Xu; lqShift = 9; }  // usr: 4mt x 4nt
  int mb0 = (rem >> 2) * 256, nb0 = (rem & 3) * 256;
  const short* W = jb.wt[jz];

  int tid = threadIdx.x;
  int lane = tid & 63, g = lane >> 4, r16 = lane & 15, w = tid >> 6;
  int wr2 = (w >> 2) * 128, wc2 = (w & 3) * 64;    // wave grid 2M x 4N, per-wave 128x64
  int cs8 = ((g ^ (r16 & 3) ^ ((r16 >> 2) & 3)) & 3) * 8;

  f32x4 acc[8][4];
  f32x4 zf = {0.f, 0.f, 0.f, 0.f};
  #pragma unroll
  for (int i = 0; i < 8; i++)
    #pragma unroll
    for (int j = 0; j < 4; j++) acc[i][j] = zf;

  // prologue: 3 K-steps in flight (12 loads/thread)
  stage256(X, mb0, 0, As[0], tid);
  stage256(W, nb0, 0, Bs[0], tid);
  stage256(X, mb0, 32, As[1], tid);
  stage256(W, nb0, 32, Bs[1], tid);
  stage256(X, mb0, 64, As[2], tid);
  stage256(W, nb0, 64, Bs[2], tid);

  for (int t = 0; t < 32; t++) {
    if (t < 30)      asm volatile("s_waitcnt vmcnt(8)" ::: "memory");
    else if (t == 30) asm volatile("s_waitcnt vmcnt(4)" ::: "memory");
    else              asm volatile("s_waitcnt vmcnt(0)" ::: "memory");
    asm volatile("s_barrier" ::: "memory");
    int q = t & 3;
    const short* a = As[q];
    const short* bb = Bs[q];
    bf16x8 af[8], bf[4];
    #pragma unroll
    for (int i = 0; i < 8; i++) af[i] = *(const bf16x8*)&a[(wr2 + i * 16 + r16) * 32 + cs8];
    #pragma unroll
    for (int j = 0; j < 4; j++) bf[j] = *(const bf16x8*)&bb[(wc2 + j * 16 + r16) * 32 + cs8];
    if (t + 3 < 32) {
      int kt = (t + 3) * 32;
      stage256(X, mb0, kt, As[(t + 3) & 3], tid);
      stage256(W, nb0, kt, Bs[(t + 3) & 3], tid);
    }
    __builtin_amdgcn_s_setprio(1);
    #pragma unroll
    for (int i = 0; i < 8; i++)
      #pragma unroll
      for (int j = 0; j < 4; j++)
        acc[i][j] = mfma16(af[i], bf[j], acc[i][j]);
    __builtin_amdgcn_s_setprio(0);
  }

  const float* bias = jb.bias[jz];
  float bscl = jb.bscl[jz];
  short* dst = jb.dst[jz];
  int mode = jb.mode[jz], lrows = jb.lrows[jz], off = jb.off[jz];
  int lqMask = (1 << lqShift) - 1;
  #pragma unroll
  for (int i = 0; i < 8; i++) {
    int m0 = mb0 + wr2 + i * 16 + g * 4;
    #pragma unroll
    for (int j = 0; j < 4; j++) {
      int n = nb0 + wc2 + j * 16 + r16;
      float bv = bias[n] * bscl;
      int h = n >> 6, d = n & 63;
      if (mode == 0) {
        #pragma unroll
        for (int r = 0; r < 4; r++) {
          int m = m0 + r;
          int b = m >> lqShift, l = m & lqMask;
          dst[((size_t)(b * NH + h) * lrows + off + l) * 64 + d] = f2bs(acc[i][j][r] + bv);
        }
      } else {
        int b = m0 >> lqShift, l = m0 & lqMask;
        size_t base = ((size_t)(b * NH + h) * 64 + d) * 1536 + off + l;
        *(uint2*)(dst + base) = make_uint2(pack2(acc[i][j][0] + bv, acc[i][j][1] + bv),
                                           pack2(acc[i][j][2] + bv, acc[i][j][3] + bv));
      }
    }
  }
}

// ---------------- GEMM staging for 128x128 (ff): tile [128 rows][32 k] = 8KB ----------------
__device__ __forceinline__ void stage_g(const short* __restrict__ src, int row0, int kt,
                                        short* buf, int tid) {
  int w = tid >> 6;
  #pragma unroll
  for (int i = 0; i < 2; i++) {
    int s = i * 256 + tid;
    int row = s >> 2, c = s & 3;
    int cs = c ^ (row & 3) ^ ((row >> 2) & 3);
    gload16(src + (size_t)(row0 + row) * 1024 + kt + cs * 8,
            buf + (size_t)(i * 256 + w * 64) * 8);
  }
}

// ---------------- 128x128 bf16 GEMM mainloop (K range [k0,k1), BK=32, dbuf, 1 barrier/iter) ----------------
__device__ __forceinline__ void gemm_128(const short* __restrict__ X, const short* __restrict__ W,
                                         short* As, short* Bs,
                                         f32x4 (&acc)[4][4], int mb0, int nb0, int k0, int k1) {
  int tid = threadIdx.x;
  int lane = tid & 63, g = lane >> 4, r16 = lane & 15, w = tid >> 6;
  int wr = (w >> 1) * 64, wc = (w & 1) * 64;
  int cs8 = ((g ^ (r16 & 3) ^ ((r16 >> 2) & 3)) & 3) * 8;
  stage_g(X, mb0, k0, As, tid);
  stage_g(W, nb0, k0, Bs, tid);
  int cur = 0;
  for (int kt = k0; kt < k1; kt += 32) {
    __syncthreads();
    const short* a = As + cur * 4096;
    const short* bb = Bs + cur * 4096;
    bf16x8 af[4], bfv[4];
    #pragma unroll
    for (int i = 0; i < 4; i++) af[i]  = *(const bf16x8*)&a[(wr + i * 16 + r16) * 32 + cs8];
    #pragma unroll
    for (int i = 0; i < 4; i++) bfv[i] = *(const bf16x8*)&bb[(wc + i * 16 + r16) * 32 + cs8];
    if (kt + 32 < k1) {
      stage_g(X, mb0, kt + 32, As + (cur ^ 1) * 4096, tid);
      stage_g(W, nb0, kt + 32, Bs + (cur ^ 1) * 4096, tid);
    }
    __builtin_amdgcn_s_setprio(1);
    #pragma unroll
    for (int i = 0; i < 4; i++)
      #pragma unroll
      for (int j = 0; j < 4; j++)
        acc[i][j] = mfma16(af[i], bfv[j], acc[i][j]);
    __builtin_amdgcn_s_setprio(0);
    cur ^= 1;
  }
}

// ---------------- FF GEMM: 2 jobs, 2-way K-split, 384 blocks; f32 partials (no bias) ----------------
struct FfJobs {
  const short* A[2];
  const short* W[2];
  float* P[2];     // partials: [2][M][1024] f32
  int mrows[2];    // 2048, 1024
};

__global__ __launch_bounds__(256) void ff_gemm(FfJobs jb) {
  __shared__ short As[2 * 4096];
  __shared__ short Bs[2 * 4096];
  int w0 = blockIdx.x;                       // 384 blocks: job0 256 (16mt x 8nt x 2kh), job1 128 (8x8x2)
  int f = (w0 & 7) * 48 + (w0 >> 3);         // XCD swizzle (384 % 8 == 0)
  int jz, rem;
  if (f < 256) { jz = 0; rem = f; } else { jz = 1; rem = f - 256; }
  int kh = rem & 1;
  int nt = (rem >> 1) & 7;
  int mt = rem >> 4;
  int mb0 = mt * 128, nb0 = nt * 128, k0 = kh * 512;
  f32x4 acc[4][4];
  f32x4 zf = {0.f, 0.f, 0.f, 0.f};
  #pragma unroll
  for (int i = 0; i < 4; i++)
    #pragma unroll
    for (int j = 0; j < 4; j++) acc[i][j] = zf;
  gemm_128(jb.A[jz], jb.W[jz], As, Bs, acc, mb0, nb0, k0, k0 + 512);

  int tid = threadIdx.x, lane = tid & 63, g = lane >> 4, r16 = lane & 15, w = tid >> 6;
  int wr = (w >> 1) * 64, wc = (w & 1) * 64;
  float* P = jb.P[jz] + (size_t)kh * jb.mrows[jz] * 1024;
  #pragma unroll
  for (int i = 0; i < 4; i++) {
    int m0 = mb0 + wr + i * 16 + g * 4;
    #pragma unroll
    for (int j = 0; j < 4; j++) {
      int n = nb0 + wc + j * 16 + r16;
      #pragma unroll
      for (int r = 0; r < 4; r++)
        P[(size_t)(m0 + r) * 1024 + n] = acc[i][j][r];
    }
  }
}

// ---------------- attention staging ----------------
__device__ __forceinline__ void stage_k(const short* __restrict__ Kb, int kb, short* buf, int tid) {
  int w = tid >> 6;
  #pragma unroll
  for (int i = 0; i < 2; i++) {
    int s = i * 256 + tid;
    int row = s >> 3, c = s & 7;
    int cs = c ^ (row & 7);
    gload16(Kb + (size_t)(kb + row) * 64 + cs * 8,
            buf + (size_t)(i * 256 + w * 64) * 8);
  }
}
__device__ __forceinline__ void stage_v(const short* __restrict__ Vb, int kb, short* buf, int tid) {
  int w = tid >> 6;
  #pragma unroll
  for (int i = 0; i < 2; i++) {
    int s = i * 256 + tid;
    int row = s >> 3, c = s & 7;       // row = dh
    int cs = c ^ (row & 7);
    gload16(Vb + (size_t)row * 1536 + kb + cs * 8,
            buf + (size_t)(i * 256 + w * 64) * 8);
  }
}

// ---------------- fused masked attention: key-split 3-way, no-max softmax, 1 barrier/iter ----------------
struct AttnArgs {
  const short *Qva, *Qvb, *Kv, *VvT;
  const short *Qta, *Qtb, *Kt, *VtT;
  const int *vmask, *umask;
  const float *kmaskf;
  short *PO;
  float *PL;
};

__global__ __launch_bounds__(256) void attn_kernel(AttnArgs A) {
  __shared__ short Ks[2][64 * 64];   // 16 KB
  __shared__ short Vs[2][64 * 64];   // 16 KB
  __shared__ short Ps[4][16 * 36];   // 4.5 KB per-wave P tile
  __shared__ float kms[512];         // 2 KB additive mask for this key third

  int w0 = blockIdx.x;               // 2304 blocks
  int fidx = (w0 & 7) * 288 + (w0 >> 3);   // XCD-chunk swizzle (2304 % 8 == 0)
  int slot = fidx / 3;
  int third = fidx - slot * 3;
  int xx = slot % 24;
  int hs = slot / 24;
  int h = hs & 15;
  int b = hs >> 4;
  bool isV = xx < 16;
  int qt = isV ? xx : (xx - 16);
  int LQ = isV ? 1024 : 512;
  const short* Qsel = (third < 2) ? (isV ? A.Qva : A.Qta) : (isV ? A.Qvb : A.Qtb);
  const short* K  = isV ? A.Kv  : A.Kt;
  const short* VT = isV ? A.VvT : A.VtT;
  const int* qmask = isV ? A.vmask : A.umask;

  int tid = threadIdx.x, w = tid >> 6, lane = tid & 63, g = lane >> 4, r16 = lane & 15;
  int q = qt * 64 + w * 16 + r16;
  size_t bh = (size_t)b * NH + h;
  int k0base = third * 512;

  const short* qp = Qsel + (bh * LQ + q) * 64 + g * 8;
  bf16x8 q0 = *(const bf16x8*)qp;
  bf16x8 q1 = *(const bf16x8*)(qp + 32);
  int mqi = qmask[b * LQ + q];

  const short* Kb = K + bh * (size_t)(1536 * 64);
  const short* Vb = VT + bh * (size_t)(64 * 1536);
  const float* kmb = A.kmaskf + b * 1536 + k0base;
  if (tid < 128) *(float4*)&kms[tid * 4] = *(const float4*)(kmb + tid * 4);

  short* pw = &Ps[w][r16 * 36];
  int sw8 = r16 & 7;

  bf16x8 ones;
  #pragma unroll
  for (int i = 0; i < 8; i++) ones[i] = (__bf16)1.0f;

  f32x4 o[4];
  f32x4 lacc;
  f32x4 zf = {0.f, 0.f, 0.f, 0.f};
  #pragma unroll
  for (int i = 0; i < 4; i++) o[i] = zf;
  lacc = zf;

  stage_k(Kb, k0base, Ks[0], tid);
  stage_v(Vb, k0base, Vs[0], tid);
  int cur = 0;
  for (int kb2 = 0; kb2 < 512; kb2 += 64) {
    __syncthreads();                 // drains stage(t-1) + all waves' reads of cur^1
    const short* Kc = Ks[cur];
    const short* Vc = Vs[cur];

    float p[16];
    #pragma unroll
    for (int ko = 0; ko < 4; ko++) {
      int krow = ko * 16 + r16;
      bf16x8 k0f = *(const bf16x8*)&Kc[krow * 64 + ((g ^ sw8) * 8)];
      bf16x8 k1f = *(const bf16x8*)&Kc[krow * 64 + (((4 + g) ^ sw8) * 8)];
      __builtin_amdgcn_s_setprio(1);
      f32x4 s = mfma16(k0f, q0, zf);
      s = mfma16(k1f, q1, s);
      __builtin_amdgcn_s_setprio(0);
      float4 kf = *(const float4*)&kms[kb2 + ko * 16 + g * 4];
      p[ko * 4 + 0] = exp2f(mqi ? s[0] + kf.x : 0.0f);
      p[ko * 4 + 1] = exp2f(mqi ? s[1] + kf.y : 0.0f);
      p[ko * 4 + 2] = exp2f(mqi ? s[2] + kf.z : 0.0f);
      p[ko * 4 + 3] = exp2f(mqi ? s[3] + kf.w : 0.0f);
    }

    if (kb2 + 64 < 512) {
      stage_k(Kb, k0base + kb2 + 64, Ks[cur ^ 1], tid);
      stage_v(Vb, k0base + kb2 + 64, Vs[cur ^ 1], tid);
    }

    #pragma unroll
    for (int kk = 0; kk < 2; kk++) {
      int pB = kk * 8;
      *(uint2*)(pw + g * 4) =
          make_uint2(pack2(p[pB + 0], p[pB + 1]), pack2(p[pB + 2], p[pB + 3]));
      *(uint2*)(pw + 16 + g * 4) =
          make_uint2(pack2(p[pB + 4], p[pB + 5]), pack2(p[pB + 6], p[pB + 7]));
      bf16x8 pb = *(const bf16x8*)(pw + g * 8);
      __builtin_amdgcn_s_setprio(1);
      #pragma unroll
      for (int dg = 0; dg < 4; dg++) {
        bf16x8 vfrag = *(const bf16x8*)&Vc[(dg * 16 + r16) * 64 + (((kk * 4 + g) ^ sw8) * 8)];
        o[dg] = mfma16(vfrag, pb, o[dg]);
      }
      lacc = mfma16(ones, pb, lacc);
      __builtin_amdgcn_s_setprio(0);
    }
    cur ^= 1;
  }
  // partials: PO[slot][third][q(64)][d(64)] bf16, PL[slot][third][q]
  short* po = A.PO + ((size_t)slot * 3 + third) * 4096 + (w * 16 + r16) * 64;
  #pragma unroll
  for (int dg = 0; dg < 4; dg++)
    *(uint2*)(po + dg * 16 + g * 4) =
        make_uint2(pack2(o[dg][0], o[dg][1]), pack2(o[dg][2], o[dg][3]));
  if (g == 0)
    A.PL[((size_t)slot * 3 + third) * 64 + w * 16 + r16] = lacc[0];
}

// ---------------- combine: o = (o0+o1+o2)/(l0+l1+l2), write bf16 AO ----------------
__global__ __launch_bounds__(256) void attn_combine(const short* __restrict__ PO,
                                                    const float* __restrict__ PL,
                                                    short* __restrict__ AOv,
                                                    short* __restrict__ AOu) {
  __shared__ float linv[64];
  int w0 = blockIdx.x;               // 768 blocks
  int slot = (w0 & 7) * 96 + (w0 >> 3);
  int tid = threadIdx.x;
  const short* p0 = PO + (size_t)slot * 3 * 4096;
  const short* p1 = p0 + 4096;
  const short* p2 = p1 + 4096;
  if (tid < 64) {
    const float* pl = PL + (size_t)slot * 3 * 64;
    linv[tid] = 1.0f / (pl[tid] + pl[64 + tid] + pl[128 + tid]);
  }
  __syncthreads();
  int xx = slot % 24;
  int hs = slot / 24;
  int h = hs & 15;
  int b = hs >> 4;
  bool isV = xx < 16;
  int qt = isV ? xx : (xx - 16);
  int LQ = isV ? 1024 : 512;
  short* out = isV ? AOv : AOu;
  #pragma unroll
  for (int it = 0; it < 8; it++) {
    int idx = (it * 256 + tid) * 2;
    int q = idx >> 6, d = idx & 63;
    unsigned v0 = *(const unsigned*)(p0 + idx);
    unsigned v1 = *(const unsigned*)(p1 + idx);
    unsigned v2 = *(const unsigned*)(p2 + idx);
    float li = linv[q];
    float ax = bs2f(v0 & 0xffff) + bs2f(v1 & 0xffff) + bs2f(v2 & 0xffff);
    float ay = bs2f(v0 >> 16) + bs2f(v1 >> 16) + bs2f(v2 >> 16);
    *(unsigned*)(out + ((size_t)b * LQ + qt * 64 + q) * 1024 + h * 64 + d) =
        pack2(ax * li, ay * li);
  }
}

// ---------------- LN + ff finalize: y = LN(P0 + P1 + bias + resid) ----------------
__global__ __launch_bounds__(256) void ln_kernel(const float* __restrict__ Pv, const float* __restrict__ Pu,
                                                 const float* __restrict__ residv, const float* __restrict__ residu,
                                                 const float* __restrict__ biasv, const float* __restrict__ biasu,
                                                 float* __restrict__ yv, float* __restrict__ yu,
                                                 const float* __restrict__ gv_, const float* __restrict__ bv_,
                                                 const float* __restrict__ gu_, const float* __restrict__ bu_) {
  __shared__ float sh[8];
  int bid = blockIdx.x;
  bool isV = bid < 2048;
  int r = isV ? bid : (bid - 2048);
  size_t mrows = isV ? 2048 : 1024;
  const float* p0 = (isV ? Pv : Pu) + (size_t)r * 1024;
  const float* p1 = p0 + mrows * 1024;
  const float* resid = (isV ? residv : residu) + (size_t)r * 1024;
  const float* bias = isV ? biasv : biasu;
  const float* gam = isV ? gv_ : gu_;
  const float* bet = isV ? bv_ : bu_;
  float* y = (isV ? yv : yu) + (size_t)r * 1024;
  int tid = threadIdx.x;
  float4 a0 = *(const float4*)(p0 + tid * 4);
  float4 a1 = *(const float4*)(p1 + tid * 4);
  float4 rv = *(const float4*)(resid + tid * 4);
  float4 bb = *(const float4*)(bias + tid * 4);
  float4 v;
  v.x = a0.x + a1.x + rv.x + bb.x;
  v.y = a0.y + a1.y + rv.y + bb.y;
  v.z = a0.z + a1.z + rv.z + bb.z;
  v.w = a0.w + a1.w + rv.w + bb.w;
  float s = v.x + v.y + v.z + v.w;
  float ss = v.x * v.x + v.y * v.y + v.z * v.z + v.w * v.w;
  #pragma unroll
  for (int off = 32; off >= 1; off >>= 1) {
    s += __shfl_xor(s, off);
    ss += __shfl_xor(ss, off);
  }
  int w = tid >> 6;
  if ((tid & 63) == 0) { sh[w] = s; sh[4 + w] = ss; }
  __syncthreads();
  float st = sh[0] + sh[1] + sh[2] + sh[3];
  float sst = sh[4] + sh[5] + sh[6] + sh[7];
  float mu = st * (1.0f / 1024.0f);
  float var = sst * (1.0f / 1024.0f) - mu * mu;
  float rs = rsqrtf(var + 1e-12f);
  float4 gv = *(const float4*)(gam + tid * 4);
  float4 bv = *(const float4*)(bet + tid * 4);
  float4 ov;
  ov.x = (v.x - mu) * rs * gv.x + bv.x;
  ov.y = (v.y - mu) * rs * gv.y + bv.y;
  ov.z = (v.z - mu) * rs * gv.z + bv.z;
  ov.w = (v.w - mu) * rs * gv.w + bv.w;
  *(float4*)(y + tid * 4) = ov;
}

extern "C" void kernel_launch(void* const* d_in, const int* in_sizes, int n_in,
                              void* d_out, int out_size, void* d_ws, size_t ws_size,
                              hipStream_t stream) {
  const float* vid_feat = (const float*)d_in[0];
  const float* usr_feat = (const float*)d_in[1];
  const int* vid_mask = (const int*)d_in[2];
  const int* usr_mask = (const int*)d_in[3];
  const float* v2v_W = (const float*)d_in[4];
  const float* v2v_b = (const float*)d_in[5];
  const float* t2v_W = (const float*)d_in[6];
  const float* t2v_b = (const float*)d_in[7];
  const float* v2t_W = (const float*)d_in[8];
  const float* v2t_b = (const float*)d_in[9];
  const float* t2t_W = (const float*)d_in[10];
  const float* t2t_b = (const float*)d_in[11];
  const float* ffu_W = (const float*)d_in[12];
  const float* ffu_b = (const float*)d_in[13];
  const float* ffv_W = (const float*)d_in[14];
  const float* ffv_b = (const float*)d_in[15];
  const float* lnu_g = (const float*)d_in[16];
  const float* lnu_b = (const float*)d_in[17];
  const float* lnv_g = (const float*)d_in[18];
  const float* lnv_b = (const float*)d_in[19];

  const size_t WM = 1024 * 1024;
  char* ws = (char*)d_ws;
  size_t off = 0;
  auto alloc = [&](size_t bytes) -> void* {
    void* p = ws + off;
    off += (bytes + 255) & ~(size_t)255;
    return p;
  };
  short* Xv  = (short*)alloc((size_t)2048 * 1024 * 2);
  short* Xu  = (short*)alloc((size_t)1024 * 1024 * 2);
  short* Wt  = (short*)alloc((size_t)14 * WM * 2);
  short* Qva = (short*)alloc((size_t)2 * NH * 1024 * 64 * 2);
  short* Qvb = (short*)alloc((size_t)2 * NH * 1024 * 64 * 2);
  short* Kv  = (short*)alloc((size_t)2 * NH * 1536 * 64 * 2);
  short* VvT = (short*)alloc((size_t)2 * NH * 64 * 1536 * 2);
  short* Qta = (short*)alloc((size_t)2 * NH * 512 * 64 * 2);
  short* Qtb = (short*)alloc((size_t)2 * NH * 512 * 64 * 2);
  short* Kt  = (short*)alloc((size_t)2 * NH * 1536 * 64 * 2);
  short* VtT = (short*)alloc((size_t)2 * NH * 64 * 1536 * 2);
  short* AOv = (short*)alloc((size_t)2048 * 1024 * 2);
  short* AOu = (short*)alloc((size_t)1024 * 1024 * 2);
  float* kmf = (float*)alloc((size_t)2 * 1536 * 4);
  short* PO  = (short*)alloc((size_t)768 * 3 * 4096 * 2);   // 18.9 MB bf16 partial O
  float* PL  = (float*)alloc((size_t)768 * 3 * 64 * 4);     // partial l
  float* Pv  = (float*)alloc((size_t)2 * 2048 * 1024 * 4);  // ff partials vid (16.8 MB)
  float* Pu  = (float*)alloc((size_t)2 * 1024 * 1024 * 4);  // ff partials usr (8.4 MB)

  // 1+2) weights transpose + activation conv + mask, one launch
  WPtrs wp;
  wp.s[0] = v2v_W; wp.s[1] = v2v_W + WM; wp.s[2] = v2v_W + 2 * WM;
  wp.s[3] = t2v_W; wp.s[4] = t2v_W + WM; wp.s[5] = t2v_W + 2 * WM;
  wp.s[6] = v2t_W; wp.s[7] = v2t_W + WM; wp.s[8] = v2t_W + 2 * WM;
  wp.s[9] = t2t_W; wp.s[10] = t2t_W + WM; wp.s[11] = t2t_W + 2 * WM;
  wp.s[12] = ffu_W; wp.s[13] = ffv_W;
  wtrans_prep_kernel<<<dim3(16, 16, 27), 256, 0, stream>>>(wp, Wt, vid_feat, usr_feat,
                                                           Xv, Xu, vid_mask, usr_mask, kmf);

  // 3) projection GEMMs: 12 jobs, 288 blocks x 512 threads (256^2 tiles, 4-deep pipeline)
  ProjJobs jp;
  jp.wt[0] = Wt + 0 * WM;  jp.dst[0] = Qva; jp.bias[0] = v2v_b;        jp.bscl[0] = SCL2E; jp.mode[0] = 0; jp.lrows[0] = 1024; jp.off[0] = 0;
  jp.wt[1] = Wt + 1 * WM;  jp.dst[1] = Kv;  jp.bias[1] = v2v_b + 1024; jp.bscl[1] = 1.0f;  jp.mode[1] = 0; jp.lrows[1] = 1536; jp.off[1] = 0;
  jp.wt[2] = Wt + 2 * WM;  jp.dst[2] = VvT; jp.bias[2] = v2v_b + 2048; jp.bscl[2] = 1.0f;  jp.mode[2] = 1; jp.lrows[2] = 0;    jp.off[2] = 0;
  jp.wt[3] = Wt + 3 * WM;  jp.dst[3] = Qvb; jp.bias[3] = t2v_b;        jp.bscl[3] = SCL2E; jp.mode[3] = 0; jp.lrows[3] = 1024; jp.off[3] = 0;
  jp.wt[4] = Wt + 7 * WM;  jp.dst[4] = Kt;  jp.bias[4] = v2t_b + 1024; jp.bscl[4] = 1.0f;  jp.mode[4] = 0; jp.lrows[4] = 1536; jp.off[4] = 0;
  jp.wt[5] = Wt + 8 * WM;  jp.dst[5] = VtT; jp.bias[5] = v2t_b + 2048; jp.bscl[5] = 1.0f;  jp.mode[5] = 1; jp.lrows[5] = 0;    jp.off[5] = 0;
  jp.wt[6] = Wt + 4 * WM;  jp.dst[6] = Kv;  jp.bias[6] = t2v_b + 1024; jp.bscl[6] = 1.0f;  jp.mode[6] = 0; jp.lrows[6] = 1536; jp.off[6] = 1024;
  jp.wt[7] = Wt + 5 * WM;  jp.dst[7] = VvT; jp.bias[7] = t2v_b + 2048; jp.bscl[7] = 1.0f;  jp.mode[7] = 1; jp.lrows[7] = 0;    jp.off[7] = 1024;
  jp.wt[8] = Wt + 6 * WM;  jp.dst[8] = Qta; jp.bias[8] = v2t_b;        jp.bscl[8] = SCL2E; jp.mode[8] = 0; jp.lrows[8] = 512;  jp.off[8] = 0;
  jp.wt[9] = Wt + 9 * WM;  jp.dst[9] = Qtb; jp.bias[9] = t2t_b;        jp.bscl[9] = SCL2E; jp.mode[9] = 0; jp.lrows[9] = 512;  jp.off[9] = 0;
  jp.wt[10] = Wt + 10 * WM; jp.dst[10] = Kt;  jp.bias[10] = t2t_b + 1024; jp.bscl[10] = 1.0f; jp.mode[10] = 0; jp.lrows[10] = 1536; jp.off[10] = 1024;
  jp.wt[11] = Wt + 11 * WM; jp.dst[11] = VtT; jp.bias[11] = t2t_b + 2048; jp.bscl[11] = 1.0f; jp.mode[11] = 1; jp.lrows[11] = 0;    jp.off[11] = 1024;
  proj_gemm256<<<288, 512, 0, stream>>>(Xv, Xu, jp);

  // 4) attention: key-split 3-way (bf16 partials), then separate combine
  AttnArgs aa;
  aa.Qva = Qva; aa.Qvb = Qvb; aa.Kv = Kv; aa.VvT = VvT;
  aa.Qta = Qta; aa.Qtb = Qtb; aa.Kt = Kt; aa.VtT = VtT;
  aa.vmask = vid_mask; aa.umask = usr_mask; aa.kmaskf = kmf;
  aa.PO = PO; aa.PL = PL;
  attn_kernel<<<2304, 256, 0, stream>>>(aa);
  attn_combine<<<768, 256, 0, stream>>>(PO, PL, AOv, AOu);

  // 5) FF (K-split 2-way, f32 partials), then LN finalize (adds partials + bias + resid)
  float* out_v = (float*)d_out;
  float* out_u = (float*)d_out + (size_t)2 * 1024 * 1024;
  FfJobs jf;
  jf.A[0] = AOv; jf.W[0] = Wt + 13 * WM; jf.P[0] = Pv; jf.mrows[0] = 2048;
  jf.A[1] = AOu; jf.W[1] = Wt + 12 * WM; jf.P[1] = Pu; jf.mrows[1] = 1024;
  ff_gemm<<<384, 256, 0, stream>>>(jf);
  ln_kernel<<<3072, 256, 0, stream>>>(Pv, Pu, vid_feat, usr_feat, ffv_b, ffu_b,
                                      out_v, out_u, lnv_g, lnv_b, lnu_g, lnu_b);
}

// Round 15
// 148.694 us; speedup vs baseline: 1.1286x; 1.1286x over previous
//
#include <hip/hip_runtime.h>
#include <hip/hip_bf16.h>

// SegFormerXAttention: B=2, LV=1024, LT=512, D=1024, H=16, DH=64
#define NH 16

typedef __attribute__((ext_vector_type(4))) float f32x4;
typedef __attribute__((ext_vector_type(8))) __bf16 bf16x8;

#define SCL2E 0.18033688011112042f   // (1/sqrt(64)) * log2(e)

__device__ __forceinline__ short f2bs(float f) {
  union { __bf16 h; short s; } x; x.h = (__bf16)f; return x.s;
}
__device__ __forceinline__ unsigned pack2(float a, float b) {
  union { __bf16 h[2]; unsigned u; } x;
  x.h[0] = (__bf16)a; x.h[1] = (__bf16)b; return x.u;
}
__device__ __forceinline__ float bs2f(unsigned short u) {
  union { unsigned u; float f; } x; x.u = (unsigned)u << 16; return x.f;
}

__device__ __forceinline__ f32x4 mfma16(bf16x8 a, bf16x8 b, f32x4 c) {
  return __builtin_amdgcn_mfma_f32_16x16x32_bf16(a, b, c, 0, 0, 0);
}

// async global->LDS, 16B per lane. LDS dest = wave-uniform base + lane*16.
__device__ __forceinline__ void gload16(const void* g, void* lds) {
  __builtin_amdgcn_global_load_lds(
      (const __attribute__((address_space(1))) void*)(unsigned long long)(g),
      (__attribute__((address_space(3))) void*)(unsigned)(unsigned long long)(lds),
      16, 0, 0);
}

// ---------------- weight transpose + activation conv + mask, ONE launch ----------------
struct WPtrs { const float* s[14]; };

__global__ __launch_bounds__(256) void wtrans_prep_kernel(WPtrs p, short* __restrict__ wt,
                                                          const float* __restrict__ vf, const float* __restrict__ uf,
                                                          short* __restrict__ Xv, short* __restrict__ Xu,
                                                          const int* __restrict__ vm, const int* __restrict__ um,
                                                          float* __restrict__ kmf) {
  int z = blockIdx.z;
  if (z >= 14) {
    int pid = (z - 14) * 256 + blockIdx.y * 16 + blockIdx.x;
    if (pid >= 3084) return;
    if (pid < 2048) {
      int i = pid * 256 + threadIdx.x;
      float4 v = *(const float4*)(vf + (size_t)i * 4);
      *(uint2*)(Xv + (size_t)i * 4) = make_uint2(pack2(v.x, v.y), pack2(v.z, v.w));
    } else if (pid < 3072) {
      int i = (pid - 2048) * 256 + threadIdx.x;
      float4 v = *(const float4*)(uf + (size_t)i * 4);
      *(uint2*)(Xu + (size_t)i * 4) = make_uint2(pack2(v.x, v.y), pack2(v.z, v.w));
    } else {
      int i = (pid - 3072) * 256 + threadIdx.x;
      if (i < 2 * 1536) {
        int b = i / 1536, k = i - b * 1536;
        int valid = (k < 1024) ? vm[b * 1024 + k] : um[b * 512 + (k - 1024)];
        kmf[i] = valid ? 0.0f : -1e35f;
      }
    }
    return;
  }
  __shared__ float t[64][65];
  const float* src = p.s[z];
  short* dst = wt + (size_t)z * 1024 * 1024;
  float scl = (z == 0 || z == 3 || z == 6 || z == 9) ? SCL2E : 1.0f;  // Q projections
  int kb = blockIdx.y * 64, nb = blockIdx.x * 64;
  int c = threadIdx.x & 63, r0 = threadIdx.x >> 6;
  #pragma unroll
  for (int i = 0; i < 16; i++) {
    int r = r0 + i * 4;
    t[r][c] = src[(size_t)(kb + r) * 1024 + nb + c];
  }
  __syncthreads();
  #pragma unroll
  for (int i = 0; i < 16; i++) {
    int r = r0 + i * 4;
    dst[(size_t)(nb + r) * 1024 + kb + c] = f2bs(t[c][r] * scl);
  }
}

// ---------------- GEMM staging: tile [128 rows][32 k] bf16 = 8KB ----------------
__device__ __forceinline__ void stage_g(const short* __restrict__ src, int row0, int kt,
                                        short* buf, int tid) {
  int w = tid >> 6;
  #pragma unroll
  for (int i = 0; i < 2; i++) {
    int s = i * 256 + tid;
    int row = s >> 2, c = s & 3;
    int cs = c ^ (row & 3) ^ ((row >> 2) & 3);
    gload16(src + (size_t)(row0 + row) * 1024 + kt + cs * 8,
            buf + (size_t)(i * 256 + w * 64) * 8);
  }
}

// ---------------- 128x128 bf16 GEMM mainloop (K range [k0,k1), BK=32, dbuf, 1 barrier/iter) ----------------
__device__ __forceinline__ void gemm_128(const short* __restrict__ X, const short* __restrict__ W,
                                         short* As, short* Bs,
                                         f32x4 (&acc)[4][4], int mb0, int nb0, int k0, int k1) {
  int tid = threadIdx.x;
  int lane = tid & 63, g = lane >> 4, r16 = lane & 15, w = tid >> 6;
  int wr = (w >> 1) * 64, wc = (w & 1) * 64;
  int cs8 = ((g ^ (r16 & 3) ^ ((r16 >> 2) & 3)) & 3) * 8;
  stage_g(X, mb0, k0, As, tid);
  stage_g(W, nb0, k0, Bs, tid);
  int cur = 0;
  for (int kt = k0; kt < k1; kt += 32) {
    __syncthreads();
    const short* a = As + cur * 4096;
    const short* bb = Bs + cur * 4096;
    bf16x8 af[4], bfv[4];
    #pragma unroll
    for (int i = 0; i < 4; i++) af[i]  = *(const bf16x8*)&a[(wr + i * 16 + r16) * 32 + cs8];
    #pragma unroll
    for (int i = 0; i < 4; i++) bfv[i] = *(const bf16x8*)&bb[(wc + i * 16 + r16) * 32 + cs8];
    if (kt + 32 < k1) {
      stage_g(X, mb0, kt + 32, As + (cur ^ 1) * 4096, tid);
      stage_g(W, nb0, kt + 32, Bs + (cur ^ 1) * 4096, tid);
    }
    __builtin_amdgcn_s_setprio(1);
    #pragma unroll
    for (int i = 0; i < 4; i++)
      #pragma unroll
      for (int j = 0; j < 4; j++)
        acc[i][j] = mfma16(af[i], bfv[j], acc[i][j]);
    __builtin_amdgcn_s_setprio(0);
    cur ^= 1;
  }
}

// ---------------- projection GEMMs: 12 jobs, compact 1152-block grid ----------------
struct ProjJobs {
  const short* wt[12];
  short* dst[12];
  const float* bias[12];
  float bscl[12];
  int mode[12];    // 0 = QK layout [B,H,lrows,64] (+row off), 1 = V^T layout [B,H,64,1536] (+col off)
  int lrows[12];
  int off[12];
};

__global__ __launch_bounds__(256) void proj_gemm(const short* __restrict__ Xv,
                                                 const short* __restrict__ Xu, ProjJobs jb) {
  __shared__ short As[2 * 4096];
  __shared__ short Bs[2 * 4096];
  int w0 = blockIdx.x;                       // 1152 blocks
  int f = (w0 & 7) * 144 + (w0 >> 3);        // XCD-chunk swizzle (1152 % 8 == 0)
  int jz, rem, lqShift;
  const short* X;
  if (f < 768) { jz = f >> 7; rem = f & 127; X = Xv; lqShift = 10; }
  else { int f2 = f - 768; jz = 6 + (f2 >> 6); rem = f2 & 63; X = Xu; lqShift = 9; }
  int mb0 = (rem >> 3) * 128, nb0 = (rem & 7) * 128;
  f32x4 acc[4][4];
  f32x4 zf = {0.f, 0.f, 0.f, 0.f};
  #pragma unroll
  for (int i = 0; i < 4; i++)
    #pragma unroll
    for (int j = 0; j < 4; j++) acc[i][j] = zf;
  gemm_128(X, jb.wt[jz], As, Bs, acc, mb0, nb0, 0, 1024);

  int tid = threadIdx.x, lane = tid & 63, g = lane >> 4, r16 = lane & 15, w = tid >> 6;
  int wr = (w >> 1) * 64, wc = (w & 1) * 64;
  const float* bias = jb.bias[jz];
  float bscl = jb.bscl[jz];
  short* dst = jb.dst[jz];
  int mode = jb.mode[jz], lrows = jb.lrows[jz], off = jb.off[jz];
  int lqMask = (1 << lqShift) - 1;
  #pragma unroll
  for (int i = 0; i < 4; i++) {
    int m0 = mb0 + wr + i * 16 + g * 4;
    #pragma unroll
    for (int j = 0; j < 4; j++) {
      int n = nb0 + wc + j * 16 + r16;
      float bv = bias[n] * bscl;
      int h = n >> 6, d = n & 63;
      if (mode == 0) {
        #pragma unroll
        for (int r = 0; r < 4; r++) {
          int m = m0 + r;
          int b = m >> lqShift, l = m & lqMask;
          dst[((size_t)(b * NH + h) * lrows + off + l) * 64 + d] = f2bs(acc[i][j][r] + bv);
        }
      } else {
        int b = m0 >> lqShift, l = m0 & lqMask;
        size_t base = ((size_t)(b * NH + h) * 64 + d) * 1536 + off + l;
        *(uint2*)(dst + base) = make_uint2(pack2(acc[i][j][0] + bv, acc[i][j][1] + bv),
                                           pack2(acc[i][j][2] + bv, acc[i][j][3] + bv));
      }
    }
  }
}

// ---------------- FF GEMM: 2 jobs, 2-way K-split, 384 blocks; bf16 partials (no bias) ----------------
struct FfJobs {
  const short* A[2];
  const short* W[2];
  short* P[2];     // partials: [2][M][1024] bf16
  int mrows[2];    // 2048, 1024
};

__global__ __launch_bounds__(256) void ff_gemm(FfJobs jb) {
  __shared__ short As[2 * 4096];
  __shared__ short Bs[2 * 4096];
  int w0 = blockIdx.x;                       // 384 blocks: job0 256 (16mt x 8nt x 2kh), job1 128 (8x8x2)
  int f = (w0 & 7) * 48 + (w0 >> 3);         // XCD swizzle (384 % 8 == 0)
  int jz, rem;
  if (f < 256) { jz = 0; rem = f; } else { jz = 1; rem = f - 256; }
  int kh = rem & 1;
  int nt = (rem >> 1) & 7;
  int mt = rem >> 4;
  int mb0 = mt * 128, nb0 = nt * 128, k0 = kh * 512;
  f32x4 acc[4][4];
  f32x4 zf = {0.f, 0.f, 0.f, 0.f};
  #pragma unroll
  for (int i = 0; i < 4; i++)
    #pragma unroll
    for (int j = 0; j < 4; j++) acc[i][j] = zf;
  gemm_128(jb.A[jz], jb.W[jz], As, Bs, acc, mb0, nb0, k0, k0 + 512);

  int tid = threadIdx.x, lane = tid & 63, g = lane >> 4, r16 = lane & 15, w = tid >> 6;
  int wr = (w >> 1) * 64, wc = (w & 1) * 64;
  short* P = jb.P[jz] + (size_t)kh * jb.mrows[jz] * 1024;
  #pragma unroll
  for (int i = 0; i < 4; i++) {
    int m0 = mb0 + wr + i * 16 + g * 4;
    #pragma unroll
    for (int j = 0; j < 4; j++) {
      int n = nb0 + wc + j * 16 + r16;
      #pragma unroll
      for (int r = 0; r < 4; r++)
        P[(size_t)(m0 + r) * 1024 + n] = f2bs(acc[i][j][r]);
    }
  }
}

// ---------------- attention staging ----------------
__device__ __forceinline__ void stage_k(const short* __restrict__ Kb, int kb, short* buf, int tid) {
  int w = tid >> 6;
  #pragma unroll
  for (int i = 0; i < 2; i++) {
    int s = i * 256 + tid;
    int row = s >> 3, c = s & 7;
    int cs = c ^ (row & 7);
    gload16(Kb + (size_t)(kb + row) * 64 + cs * 8,
            buf + (size_t)(i * 256 + w * 64) * 8);
  }
}
__device__ __forceinline__ void stage_v(const short* __restrict__ Vb, int kb, short* buf, int tid) {
  int w = tid >> 6;
  #pragma unroll
  for (int i = 0; i < 2; i++) {
    int s = i * 256 + tid;
    int row = s >> 3, c = s & 7;       // row = dh
    int cs = c ^ (row & 7);
    gload16(Vb + (size_t)row * 1536 + kb + cs * 8,
            buf + (size_t)(i * 256 + w * 64) * 8);
  }
}

// ---------------- fused masked attention: key-split 3-way, no-max softmax, 1 barrier/iter ----------------
struct AttnArgs {
  const short *Qva, *Qvb, *Kv, *VvT;
  const short *Qta, *Qtb, *Kt, *VtT;
  const int *vmask, *umask;
  const float *kmaskf;
  short *PO;
  float *PL;
};

__global__ __launch_bounds__(256) void attn_kernel(AttnArgs A) {
  __shared__ short Ks[2][64 * 64];   // 16 KB
  __shared__ short Vs[2][64 * 64];   // 16 KB
  __shared__ short Ps[4][16 * 36];   // 4.5 KB per-wave P tile
  __shared__ float kms[512];         // 2 KB additive mask for this key third

  int w0 = blockIdx.x;               // 2304 blocks
  int fidx = (w0 & 7) * 288 + (w0 >> 3);   // XCD-chunk swizzle (2304 % 8 == 0)
  int slot = fidx / 3;
  int third = fidx - slot * 3;
  int xx = slot % 24;
  int hs = slot / 24;
  int h = hs & 15;
  int b = hs >> 4;
  bool isV = xx < 16;
  int qt = isV ? xx : (xx - 16);
  int LQ = isV ? 1024 : 512;
  const short* Qsel = (third < 2) ? (isV ? A.Qva : A.Qta) : (isV ? A.Qvb : A.Qtb);
  const short* K  = isV ? A.Kv  : A.Kt;
  const short* VT = isV ? A.VvT : A.VtT;
  const int* qmask = isV ? A.vmask : A.umask;

  int tid = threadIdx.x, w = tid >> 6, lane = tid & 63, g = lane >> 4, r16 = lane & 15;
  int q = qt * 64 + w * 16 + r16;
  size_t bh = (size_t)b * NH + h;
  int k0base = third * 512;

  const short* qp = Qsel + (bh * LQ + q) * 64 + g * 8;
  bf16x8 q0 = *(const bf16x8*)qp;
  bf16x8 q1 = *(const bf16x8*)(qp + 32);
  int mqi = qmask[b * LQ + q];

  const short* Kb = K + bh * (size_t)(1536 * 64);
  const short* Vb = VT + bh * (size_t)(64 * 1536);
  const float* kmb = A.kmaskf + b * 1536 + k0base;
  if (tid < 128) *(float4*)&kms[tid * 4] = *(const float4*)(kmb + tid * 4);

  short* pw = &Ps[w][r16 * 36];
  int sw8 = r16 & 7;

  bf16x8 ones;
  #pragma unroll
  for (int i = 0; i < 8; i++) ones[i] = (__bf16)1.0f;

  f32x4 o[4];
  f32x4 lacc;
  f32x4 zf = {0.f, 0.f, 0.f, 0.f};
  #pragma unroll
  for (int i = 0; i < 4; i++) o[i] = zf;
  lacc = zf;

  stage_k(Kb, k0base, Ks[0], tid);
  stage_v(Vb, k0base, Vs[0], tid);
  int cur = 0;
  for (int kb2 = 0; kb2 < 512; kb2 += 64) {
    __syncthreads();                 // drains stage(t-1) + all waves' reads of cur^1
    const short* Kc = Ks[cur];
    const short* Vc = Vs[cur];

    float p[16];
    #pragma unroll
    for (int ko = 0; ko < 4; ko++) {
      int krow = ko * 16 + r16;
      bf16x8 k0f = *(const bf16x8*)&Kc[krow * 64 + ((g ^ sw8) * 8)];
      bf16x8 k1f = *(const bf16x8*)&Kc[krow * 64 + (((4 + g) ^ sw8) * 8)];
      __builtin_amdgcn_s_setprio(1);
      f32x4 s = mfma16(k0f, q0, zf);
      s = mfma16(k1f, q1, s);
      __builtin_amdgcn_s_setprio(0);
      float4 kf = *(const float4*)&kms[kb2 + ko * 16 + g * 4];
      p[ko * 4 + 0] = exp2f(mqi ? s[0] + kf.x : 0.0f);
      p[ko * 4 + 1] = exp2f(mqi ? s[1] + kf.y : 0.0f);
      p[ko * 4 + 2] = exp2f(mqi ? s[2] + kf.z : 0.0f);
      p[ko * 4 + 3] = exp2f(mqi ? s[3] + kf.w : 0.0f);
    }

    if (kb2 + 64 < 512) {
      stage_k(Kb, k0base + kb2 + 64, Ks[cur ^ 1], tid);
      stage_v(Vb, k0base + kb2 + 64, Vs[cur ^ 1], tid);
    }

    #pragma unroll
    for (int kk = 0; kk < 2; kk++) {
      int pB = kk * 8;
      *(uint2*)(pw + g * 4) =
          make_uint2(pack2(p[pB + 0], p[pB + 1]), pack2(p[pB + 2], p[pB + 3]));
      *(uint2*)(pw + 16 + g * 4) =
          make_uint2(pack2(p[pB + 4], p[pB + 5]), pack2(p[pB + 6], p[pB + 7]));
      bf16x8 pb = *(const bf16x8*)(pw + g * 8);
      __builtin_amdgcn_s_setprio(1);
      #pragma unroll
      for (int dg = 0; dg < 4; dg++) {
        bf16x8 vfrag = *(const bf16x8*)&Vc[(dg * 16 + r16) * 64 + (((kk * 4 + g) ^ sw8) * 8)];
        o[dg] = mfma16(vfrag, pb, o[dg]);
      }
      lacc = mfma16(ones, pb, lacc);
      __builtin_amdgcn_s_setprio(0);
    }
    cur ^= 1;
  }
  // partials: PO[slot][third][q(64)][d(64)] bf16, PL[slot][third][q]
  short* po = A.PO + ((size_t)slot * 3 + third) * 4096 + (w * 16 + r16) * 64;
  #pragma unroll
  for (int dg = 0; dg < 4; dg++)
    *(uint2*)(po + dg * 16 + g * 4) =
        make_uint2(pack2(o[dg][0], o[dg][1]), pack2(o[dg][2], o[dg][3]));
  if (g == 0)
    A.PL[((size_t)slot * 3 + third) * 64 + w * 16 + r16] = lacc[0];
}

// ---------------- combine: o = (o0+o1+o2)/(l0+l1+l2), write bf16 AO ----------------
__global__ __launch_bounds__(256) void attn_combine(const short* __restrict__ PO,
                                                    const float* __restrict__ PL,
                                                    short* __restrict__ AOv,
                                                    short* __restrict__ AOu) {
  __shared__ float linv[64];
  int w0 = blockIdx.x;               // 768 blocks
  int slot = (w0 & 7) * 96 + (w0 >> 3);
  int tid = threadIdx.x;
  const short* p0 = PO + (size_t)slot * 3 * 4096;
  const short* p1 = p0 + 4096;
  const short* p2 = p1 + 4096;
  if (tid < 64) {
    const float* pl = PL + (size_t)slot * 3 * 64;
    linv[tid] = 1.0f / (pl[tid] + pl[64 + tid] + pl[128 + tid]);
  }
  __syncthreads();
  int xx = slot % 24;
  int hs = slot / 24;
  int h = hs & 15;
  int b = hs >> 4;
  bool isV = xx < 16;
  int qt = isV ? xx : (xx - 16);
  int LQ = isV ? 1024 : 512;
  short* out = isV ? AOv : AOu;
  #pragma unroll
  for (int it = 0; it < 8; it++) {
    int idx = (it * 256 + tid) * 2;
    int q = idx >> 6, d = idx & 63;
    unsigned v0 = *(const unsigned*)(p0 + idx);
    unsigned v1 = *(const unsigned*)(p1 + idx);
    unsigned v2 = *(const unsigned*)(p2 + idx);
    float li = linv[q];
    float ax = bs2f(v0 & 0xffff) + bs2f(v1 & 0xffff) + bs2f(v2 & 0xffff);
    float ay = bs2f(v0 >> 16) + bs2f(v1 >> 16) + bs2f(v2 >> 16);
    *(unsigned*)(out + ((size_t)b * LQ + qt * 64 + q) * 1024 + h * 64 + d) =
        pack2(ax * li, ay * li);
  }
}

// ---------------- LN + ff finalize: y = LN(P0 + P1 + bias + resid), bf16 partials ----------------
__global__ __launch_bounds__(256) void ln_kernel(const short* __restrict__ Pv, const short* __restrict__ Pu,
                                                 const float* __restrict__ residv, const float* __restrict__ residu,
                                                 const float* __restrict__ biasv, const float* __restrict__ biasu,
                                                 float* __restrict__ yv, float* __restrict__ yu,
                                                 const float* __restrict__ gv_, const float* __restrict__ bv_,
                                                 const float* __restrict__ gu_, const float* __restrict__ bu_) {
  __shared__ float sh[8];
  int bid = blockIdx.x;
  bool isV = bid < 2048;
  int r = isV ? bid : (bid - 2048);
  size_t mrows = isV ? 2048 : 1024;
  const short* p0 = (isV ? Pv : Pu) + (size_t)r * 1024;
  const short* p1 = p0 + mrows * 1024;
  const float* resid = (isV ? residv : residu) + (size_t)r * 1024;
  const float* bias = isV ? biasv : biasu;
  const float* gam = isV ? gv_ : gu_;
  const float* bet = isV ? bv_ : bu_;
  float* y = (isV ? yv : yu) + (size_t)r * 1024;
  int tid = threadIdx.x;
  uint2 u0 = *(const uint2*)(p0 + tid * 4);
  uint2 u1 = *(const uint2*)(p1 + tid * 4);
  float4 rv = *(const float4*)(resid + tid * 4);
  float4 bb = *(const float4*)(bias + tid * 4);
  float4 v;
  v.x = bs2f(u0.x & 0xffff) + bs2f(u1.x & 0xffff) + rv.x + bb.x;
  v.y = bs2f(u0.x >> 16)    + bs2f(u1.x >> 16)    + rv.y + bb.y;
  v.z = bs2f(u0.y & 0xffff) + bs2f(u1.y & 0xffff) + rv.z + bb.z;
  v.w = bs2f(u0.y >> 16)    + bs2f(u1.y >> 16)    + rv.w + bb.w;
  float s = v.x + v.y + v.z + v.w;
  float ss = v.x * v.x + v.y * v.y + v.z * v.z + v.w * v.w;
  #pragma unroll
  for (int off = 32; off >= 1; off >>= 1) {
    s += __shfl_xor(s, off);
    ss += __shfl_xor(ss, off);
  }
  int w = tid >> 6;
  if ((tid & 63) == 0) { sh[w] = s; sh[4 + w] = ss; }
  __syncthreads();
  float st = sh[0] + sh[1] + sh[2] + sh[3];
  float sst = sh[4] + sh[5] + sh[6] + sh[7];
  float mu = st * (1.0f / 1024.0f);
  float var = sst * (1.0f / 1024.0f) - mu * mu;
  float rs = rsqrtf(var + 1e-12f);
  float4 gv = *(const float4*)(gam + tid * 4);
  float4 bv = *(const float4*)(bet + tid * 4);
  float4 ov;
  ov.x = (v.x - mu) * rs * gv.x + bv.x;
  ov.y = (v.y - mu) * rs * gv.y + bv.y;
  ov.z = (v.z - mu) * rs * gv.z + bv.z;
  ov.w = (v.w - mu) * rs * gv.w + bv.w;
  *(float4*)(y + tid * 4) = ov;
}

extern "C" void kernel_launch(void* const* d_in, const int* in_sizes, int n_in,
                              void* d_out, int out_size, void* d_ws, size_t ws_size,
                              hipStream_t stream) {
  const float* vid_feat = (const float*)d_in[0];
  const float* usr_feat = (const float*)d_in[1];
  const int* vid_mask = (const int*)d_in[2];
  const int* usr_mask = (const int*)d_in[3];
  const float* v2v_W = (const float*)d_in[4];
  const float* v2v_b = (const float*)d_in[5];
  const float* t2v_W = (const float*)d_in[6];
  const float* t2v_b = (const float*)d_in[7];
  const float* v2t_W = (const float*)d_in[8];
  const float* v2t_b = (const float*)d_in[9];
  const float* t2t_W = (const float*)d_in[10];
  const float* t2t_b = (const float*)d_in[11];
  const float* ffu_W = (const float*)d_in[12];
  const float* ffu_b = (const float*)d_in[13];
  const float* ffv_W = (const float*)d_in[14];
  const float* ffv_b = (const float*)d_in[15];
  const float* lnu_g = (const float*)d_in[16];
  const float* lnu_b = (const float*)d_in[17];
  const float* lnv_g = (const float*)d_in[18];
  const float* lnv_b = (const float*)d_in[19];

  const size_t WM = 1024 * 1024;
  char* ws = (char*)d_ws;
  size_t off = 0;
  auto alloc = [&](size_t bytes) -> void* {
    void* p = ws + off;
    off += (bytes + 255) & ~(size_t)255;
    return p;
  };
  short* Xv  = (short*)alloc((size_t)2048 * 1024 * 2);
  short* Xu  = (short*)alloc((size_t)1024 * 1024 * 2);
  short* Wt  = (short*)alloc((size_t)14 * WM * 2);
  short* Qva = (short*)alloc((size_t)2 * NH * 1024 * 64 * 2);
  short* Qvb = (short*)alloc((size_t)2 * NH * 1024 * 64 * 2);
  short* Kv  = (short*)alloc((size_t)2 * NH * 1536 * 64 * 2);
  short* VvT = (short*)alloc((size_t)2 * NH * 64 * 1536 * 2);
  short* Qta = (short*)alloc((size_t)2 * NH * 512 * 64 * 2);
  short* Qtb = (short*)alloc((size_t)2 * NH * 512 * 64 * 2);
  short* Kt  = (short*)alloc((size_t)2 * NH * 1536 * 64 * 2);
  short* VtT = (short*)alloc((size_t)2 * NH * 64 * 1536 * 2);
  short* AOv = (short*)alloc((size_t)2048 * 1024 * 2);
  short* AOu = (short*)alloc((size_t)1024 * 1024 * 2);
  float* kmf = (float*)alloc((size_t)2 * 1536 * 4);
  short* PO  = (short*)alloc((size_t)768 * 3 * 4096 * 2);   // 18.9 MB bf16 partial O
  float* PL  = (float*)alloc((size_t)768 * 3 * 64 * 4);     // partial l
  short* Pv  = (short*)alloc((size_t)2 * 2048 * 1024 * 2);  // ff partials vid (8.4 MB bf16)
  short* Pu  = (short*)alloc((size_t)2 * 1024 * 1024 * 2);  // ff partials usr (4.2 MB bf16)

  // 1+2) weights transpose + activation conv + mask, one launch
  WPtrs wp;
  wp.s[0] = v2v_W; wp.s[1] = v2v_W + WM; wp.s[2] = v2v_W + 2 * WM;
  wp.s[3] = t2v_W; wp.s[4] = t2v_W + WM; wp.s[5] = t2v_W + 2 * WM;
  wp.s[6] = v2t_W; wp.s[7] = v2t_W + WM; wp.s[8] = v2t_W + 2 * WM;
  wp.s[9] = t2t_W; wp.s[10] = t2t_W + WM; wp.s[11] = t2t_W + 2 * WM;
  wp.s[12] = ffu_W; wp.s[13] = ffv_W;
  wtrans_prep_kernel<<<dim3(16, 16, 27), 256, 0, stream>>>(wp, Wt, vid_feat, usr_feat,
                                                           Xv, Xu, vid_mask, usr_mask, kmf);

  // 3) projection GEMMs: 12 jobs, compact 1152-block launch
  ProjJobs jp;
  jp.wt[0] = Wt + 0 * WM;  jp.dst[0] = Qva; jp.bias[0] = v2v_b;        jp.bscl[0] = SCL2E; jp.mode[0] = 0; jp.lrows[0] = 1024; jp.off[0] = 0;
  jp.wt[1] = Wt + 1 * WM;  jp.dst[1] = Kv;  jp.bias[1] = v2v_b + 1024; jp.bscl[1] = 1.0f;  jp.mode[1] = 0; jp.lrows[1] = 1536; jp.off[1] = 0;
  jp.wt[2] = Wt + 2 * WM;  jp.dst[2] = VvT; jp.bias[2] = v2v_b + 2048; jp.bscl[2] = 1.0f;  jp.mode[2] = 1; jp.lrows[2] = 0;    jp.off[2] = 0;
  jp.wt[3] = Wt + 3 * WM;  jp.dst[3] = Qvb; jp.bias[3] = t2v_b;        jp.bscl[3] = SCL2E; jp.mode[3] = 0; jp.lrows[3] = 1024; jp.off[3] = 0;
  jp.wt[4] = Wt + 7 * WM;  jp.dst[4] = Kt;  jp.bias[4] = v2t_b + 1024; jp.bscl[4] = 1.0f;  jp.mode[4] = 0; jp.lrows[4] = 1536; jp.off[4] = 0;
  jp.wt[5] = Wt + 8 * WM;  jp.dst[5] = VtT; jp.bias[5] = v2t_b + 2048; jp.bscl[5] = 1.0f;  jp.mode[5] = 1; jp.lrows[5] = 0;    jp.off[5] = 0;
  jp.wt[6] = Wt + 4 * WM;  jp.dst[6] = Kv;  jp.bias[6] = t2v_b + 1024; jp.bscl[6] = 1.0f;  jp.mode[6] = 0; jp.lrows[6] = 1536; jp.off[6] = 1024;
  jp.wt[7] = Wt + 5 * WM;  jp.dst[7] = VvT; jp.bias[7] = t2v_b + 2048; jp.bscl[7] = 1.0f;  jp.mode[7] = 1; jp.lrows[7] = 0;    jp.off[7] = 1024;
  jp.wt[8] = Wt + 6 * WM;  jp.dst[8] = Qta; jp.bias[8] = v2t_b;        jp.bscl[8] = SCL2E; jp.mode[8] = 0; jp.lrows[8] = 512;  jp.off[8] = 0;
  jp.wt[9] = Wt + 9 * WM;  jp.dst[9] = Qtb; jp.bias[9] = t2t_b;        jp.bscl[9] = SCL2E; jp.mode[9] = 0; jp.lrows[9] = 512;  jp.off[9] = 0;
  jp.wt[10] = Wt + 10 * WM; jp.dst[10] = Kt;  jp.bias[10] = t2t_b + 1024; jp.bscl[10] = 1.0f; jp.mode[10] = 0; jp.lrows[10] = 1536; jp.off[10] = 1024;
  jp.wt[11] = Wt + 11 * WM; jp.dst[11] = VtT; jp.bias[11] = t2t_b + 2048; jp.bscl[11] = 1.0f; jp.mode[11] = 1; jp.lrows[11] = 0;    jp.off[11] = 1024;
  proj_gemm<<<1152, 256, 0, stream>>>(Xv, Xu, jp);

  // 4) attention: key-split 3-way (bf16 partials), then separate combine
  AttnArgs aa;
  aa.Qva = Qva; aa.Qvb = Qvb; aa.Kv = Kv; aa.VvT = VvT;
  aa.Qta = Qta; aa.Qtb = Qtb; aa.Kt = Kt; aa.VtT = VtT;
  aa.vmask = vid_mask; aa.umask = usr_mask; aa.kmaskf = kmf;
  aa.PO = PO; aa.PL = PL;
  attn_kernel<<<2304, 256, 0, stream>>>(aa);
  attn_combine<<<768, 256, 0, stream>>>(PO, PL, AOv, AOu);

  // 5) FF (K-split 2-way, bf16 partials), then LN finalize (adds partials + bias + resid)
  float* out_v = (float*)d_out;
  float* out_u = (float*)d_out + (size_t)2 * 1024 * 1024;
  FfJobs jf;
  jf.A[0] = AOv; jf.W[0] = Wt + 13 * WM; jf.P[0] = Pv; jf.mrows[0] = 2048;
  jf.A[1] = AOu; jf.W[1] = Wt + 12 * WM; jf.P[1] = Pu; jf.mrows[1] = 1024;
  ff_gemm<<<384, 256, 0, stream>>>(jf);
  ln_kernel<<<3072, 256, 0, stream>>>(Pv, Pu, vid_feat, usr_feat, ffv_b, ffu_b,
                                      out_v, out_u, lnv_g, lnv_b, lnu_g, lnu_b);
}